// Round 17
// baseline (132.914 us; speedup 1.0000x reference)
//
#include <hip/hip_runtime.h>
#include <math.h>

#define NB 64
#define NP 8732
#define NC 81
#define NROWS (NB * NP)            // 558848 = 2183 * 256 exactly
#define TPB 256
#define NBLK (NROWS / TPB)         // 2183
#define SEL_TPB 1024
#define SKPT 9                     // ceil(NP/1024); i==8 valid only for tid<540
#define STAIL (NP - 8 * SEL_TPB)   // 540

// ws layout:
//   acc      : double[8]        @ 0   [0]=topK_neg [1]=ce_pos [2]=sl1 [3]=num_pos [4]=ticket
//   partials : double[NBLK*3]   @ 64
//   keys     : uint[NROWS]      @ KEY_OFF
//   acc2/out2: shadow accumulators for measurement dup-selects
#define PART_OFF 64
#define PART_BYTES (((NBLK * 3 * 8 + 63) / 64) * 64)
#define KEY_OFF  (PART_OFF + PART_BYTES)
#define ACC2_OFF (KEY_OFF + NROWS * 4)
#define OUT2_OFF (ACC2_OFF + 64)

__global__ __launch_bounds__(TPB) void mb_rows(
    const float* __restrict__ conf,
    const float* __restrict__ pred,
    const float* __restrict__ gt,
    const int*   __restrict__ labels,
    unsigned* __restrict__ keys,
    double* __restrict__ partials,
    double* __restrict__ acc)
{
    __shared__ double s_red[4][3];

    const int tid = threadIdx.x;
    const int row = blockIdx.x * TPB + tid;       // always < NROWS (exact grid)

    if (blockIdx.x == 0 && tid == 0) {
        acc[0] = 0.0; acc[1] = 0.0; acc[2] = 0.0; acc[3] = 0.0; acc[4] = 0.0;
    }

    const float* rp = conf + (size_t)row * NC;

    float4 q[20];
    #pragma unroll
    for (int i = 0; i < 20; ++i) __builtin_memcpy(&q[i], rp + 4 * i, 16);
    const float last = rp[80];

    float4 m4 = q[0];
    #pragma unroll
    for (int i = 1; i < 20; ++i) {
        m4.x = fmaxf(m4.x, q[i].x);
        m4.y = fmaxf(m4.y, q[i].y);
        m4.z = fmaxf(m4.z, q[i].z);
        m4.w = fmaxf(m4.w, q[i].w);
    }
    float M = fmaxf(fmaxf(m4.x, m4.y), fmaxf(m4.z, m4.w));
    M = fmaxf(M, last);

    float s = __expf(last - M);
    #pragma unroll
    for (int i = 0; i < 20; ++i)
        s += __expf(q[i].x - M) + __expf(q[i].y - M)
           + __expf(q[i].z - M) + __expf(q[i].w - M);

    const float lse = M + __logf(s);

    double ce = 0.0, sl = 0.0, npd = 0.0;
    const int lbl = labels[row];
    unsigned key = 0u;
    if (lbl > 0) {
        ce  = (double)(lse - rp[lbl]);
        npd = 1.0;
        const float4 pv = ((const float4*)pred)[row];
        const float4 gv = ((const float4*)gt)[row];
        float d;
        d = fabsf(pv.x - gv.x); sl += (d < 1.f) ? 0.5f * d * d : d - 0.5f;
        d = fabsf(pv.y - gv.y); sl += (d < 1.f) ? 0.5f * d * d : d - 0.5f;
        d = fabsf(pv.z - gv.z); sl += (d < 1.f) ? 0.5f * d * d : d - 0.5f;
        d = fabsf(pv.w - gv.w); sl += (d < 1.f) ? 0.5f * d * d : d - 0.5f;
    } else {
        key = __float_as_uint(lse - q[0].x) + 1u;
    }
    keys[row] = key;

    #pragma unroll
    for (int o = 32; o; o >>= 1) {
        ce  += __shfl_xor(ce, o);
        sl  += __shfl_xor(sl, o);
        npd += __shfl_xor(npd, o);
    }
    const int wid = tid >> 6, lane = tid & 63;
    if (lane == 0) { s_red[wid][0] = ce; s_red[wid][1] = sl; s_red[wid][2] = npd; }
    __syncthreads();
    if (tid == 0) {
        double a = 0, b = 0, c = 0;
        for (int w = 0; w < 4; ++w) { a += s_red[w][0]; b += s_red[w][1]; c += s_red[w][2]; }
        partials[blockIdx.x * 3 + 0] = a;
        partials[blockIdx.x * 3 + 1] = b;
        partials[blockIdx.x * 3 + 2] = c;
    }
}

__global__ __launch_bounds__(SEL_TPB) void mb_select(
    const unsigned* __restrict__ keys_g,
    const double* __restrict__ partials,
    double* __restrict__ acc,
    float* __restrict__ out)
{
    __shared__ unsigned cnt[34];
    __shared__ unsigned s_np[16], s_mx[16], s_mn[16], s_cg[16];
    __shared__ double   s_sum[16];
    __shared__ double   s_pp[3];
    __shared__ unsigned s_K, s_lo, s_hi;

    const int b = blockIdx.x, tid = threadIdx.x;
    const int lane = tid & 63, wid = tid >> 6;

    if (wid == 0) {
        double pce = 0, psl = 0, pnp = 0;
        const int j = b + (lane << 6);
        if (j < NBLK) {
            pce = partials[3 * j + 0];
            psl = partials[3 * j + 1];
            pnp = partials[3 * j + 2];
        }
        #pragma unroll
        for (int o = 32; o; o >>= 1) {
            pce += __shfl_xor(pce, o);
            psl += __shfl_xor(psl, o);
            pnp += __shfl_xor(pnp, o);
        }
        if (lane == 0) { s_pp[0] = pce; s_pp[1] = psl; s_pp[2] = pnp; }
    }

    unsigned k[SKPT];
    unsigned np = 0, mx = 0u, mn = 0xFFFFFFFFu;
    #pragma unroll
    for (int i = 0; i < SKPT; ++i) {
        unsigned key = 0u;
        if (i < 8 || tid < STAIL) {
            key = keys_g[b * NP + i * SEL_TPB + tid];
            np += (key == 0u) ? 1u : 0u;
            if (key) { mx = max(mx, key); mn = min(mn, key); }
        }
        k[i] = key;
    }
    if (tid < 34) cnt[tid] = 0u;

    #pragma unroll
    for (int o = 32; o; o >>= 1) {
        np += __shfl_xor(np, o);
        mx  = max(mx, __shfl_xor(mx, o));
        mn  = min(mn, __shfl_xor(mn, o));
    }
    if (lane == 0) { s_np[wid] = np; s_mx[wid] = mx; s_mn[wid] = mn; }
    __syncthreads();

    if (tid == 0) {
        unsigned npt = 0, MX = 0, MN = 0xFFFFFFFFu;
        for (int q = 0; q < 16; ++q) {
            npt += s_np[q];
            MX = max(MX, s_mx[q]); MN = min(MN, s_mn[q]);
        }
        atomicAdd(&acc[1], s_pp[0]);
        atomicAdd(&acc[2], s_pp[1]);
        atomicAdd(&acc[3], s_pp[2]);
        unsigned K = 3u * npt;
        const unsigned nneg = NP - npt;
        if (K > nneg) K = nneg;
        s_K = K; s_lo = MN; s_hi = MX;
    }
    __syncthreads();

    const unsigned K = s_K;
    if (K > 0) {
        unsigned lo = s_lo, hi = s_hi;
        int it = 0;
        while (lo < hi) {
            const unsigned mid = lo + ((hi - lo) >> 1);
            unsigned c = 0;
            #pragma unroll
            for (int i = 0; i < SKPT; ++i) c += (k[i] > mid) ? 1u : 0u;
            #pragma unroll
            for (int o = 32; o; o >>= 1) c += __shfl_xor(c, o);
            if (lane == 0) atomicAdd(&cnt[it], c);
            __syncthreads();
            if (cnt[it] < K) hi = mid; else lo = mid + 1;
            ++it;
        }
        const unsigned V = lo;

        double ssum = 0.0; unsigned cgt = 0;
        #pragma unroll
        for (int i = 0; i < SKPT; ++i) {
            const unsigned kk = k[i];
            if (kk > V) { ssum += (double)__uint_as_float(kk - 1u); cgt++; }
        }
        #pragma unroll
        for (int o = 32; o; o >>= 1) { ssum += __shfl_xor(ssum, o); cgt += __shfl_xor(cgt, o); }
        if (lane == 0) { s_sum[wid] = ssum; s_cg[wid] = cgt; }
        __syncthreads();
        if (tid == 0) {
            double tot = 0.0; unsigned cg = 0;
            for (int q = 0; q < 16; ++q) { tot += s_sum[q]; cg += s_cg[q]; }
            tot += (double)(K - cg) * (double)__uint_as_float(V - 1u);
            atomicAdd(&acc[0], tot);
        }
    }

    if (tid == 0) {
        __threadfence();
        const unsigned done = atomicAdd((unsigned*)(acc + 4), 1u);
        if (done == NB - 1) {
            __threadfence();
            const double topk = atomicAdd(&acc[0], 0.0);
            const double pce  = atomicAdd(&acc[1], 0.0);
            const double psl  = atomicAdd(&acc[2], 0.0);
            const double npd  = atomicAdd(&acc[3], 0.0);
            out[0] = (float)(psl / npd);            // smooth_l1 / num_pos
            out[1] = (float)((pce + topk) / npd);   // classification / num_pos
        }
    }
}

extern "C" void kernel_launch(void* const* d_in, const int* in_sizes, int n_in,
                              void* d_out, int out_size, void* d_ws, size_t ws_size,
                              hipStream_t stream)
{
    const float* conf   = (const float*)d_in[0];
    const float* pred   = (const float*)d_in[1];
    const int*   labels = (const int*)d_in[2];
    const float* gt     = (const float*)d_in[3];
    float* out = (float*)d_out;

    double*   acc      = (double*)d_ws;
    double*   partials = (double*)((char*)d_ws + PART_OFF);
    unsigned* keys     = (unsigned*)((char*)d_ws + KEY_OFF);

    // shadow targets for measurement dup-selects (never affect d_out)
    double* acc2 = (double*)((char*)d_ws + ACC2_OFF);
    float*  out2 = (float*)((char*)d_ws + OUT2_OFF);

    mb_rows<<<NBLK, TPB, 0, stream>>>(conf, pred, gt, labels, keys, partials, acc);
    mb_select<<<NB, SEL_TPB, 0, stream>>>(keys, partials, acc, out);
    // --- amplification probe: 4x duplicate select into shadows ---
    mb_select<<<NB, SEL_TPB, 0, stream>>>(keys, partials, acc2, out2);
    mb_select<<<NB, SEL_TPB, 0, stream>>>(keys, partials, acc2, out2);
    mb_select<<<NB, SEL_TPB, 0, stream>>>(keys, partials, acc2, out2);
    mb_select<<<NB, SEL_TPB, 0, stream>>>(keys, partials, acc2, out2);
}

// Round 18
// 49.609 us; speedup vs baseline: 2.6792x; 2.6792x over previous
//
#include <hip/hip_runtime.h>
#include <math.h>

#define NB 64
#define NP 8732
#define NC 81
#define NROWS (NB * NP)            // 558848 = 2183 * 256 exactly
#define TPB 256
#define NBLK (NROWS / TPB)         // 2183
#define SEL_TPB 1024
#define SKPT 9                     // ceil(NP/1024); i==8 valid only for tid<540
#define STAIL (NP - 8 * SEL_TPB)   // 540
#define NWAVE 16
#define HPAD 257                   // +1 pad: wave w's bins land on distinct banks

// ws layout:
//   acc      : double[8]        @ 0   [0]=topK_neg [1]=ce_pos [2]=sl1 [3]=num_pos [4]=ticket
//   partials : double[NBLK*3]   @ 64
//   keys     : uint[NROWS]      @ KEY_OFF   (0 = positive; else bits(bg)+1)
#define PART_OFF 64
#define PART_BYTES (((NBLK * 3 * 8 + 63) / 64) * 64)
#define KEY_OFF (PART_OFF + PART_BYTES)

__global__ __launch_bounds__(TPB) void mb_rows(
    const float* __restrict__ conf,
    const float* __restrict__ pred,
    const float* __restrict__ gt,
    const int*   __restrict__ labels,
    unsigned* __restrict__ keys,
    double* __restrict__ partials,
    double* __restrict__ acc)
{
    __shared__ double s_red[4][3];

    const int tid = threadIdx.x;
    const int row = blockIdx.x * TPB + tid;       // always < NROWS (exact grid)

    if (blockIdx.x == 0 && tid == 0) {
        acc[0] = 0.0; acc[1] = 0.0; acc[2] = 0.0; acc[3] = 0.0; acc[4] = 0.0;
    }

    const float* rp = conf + (size_t)row * NC;

    float4 q[20];
    #pragma unroll
    for (int i = 0; i < 20; ++i) __builtin_memcpy(&q[i], rp + 4 * i, 16);
    const float last = rp[80];

    float4 m4 = q[0];
    #pragma unroll
    for (int i = 1; i < 20; ++i) {
        m4.x = fmaxf(m4.x, q[i].x);
        m4.y = fmaxf(m4.y, q[i].y);
        m4.z = fmaxf(m4.z, q[i].z);
        m4.w = fmaxf(m4.w, q[i].w);
    }
    float M = fmaxf(fmaxf(m4.x, m4.y), fmaxf(m4.z, m4.w));
    M = fmaxf(M, last);

    float s = __expf(last - M);
    #pragma unroll
    for (int i = 0; i < 20; ++i)
        s += __expf(q[i].x - M) + __expf(q[i].y - M)
           + __expf(q[i].z - M) + __expf(q[i].w - M);

    const float lse = M + __logf(s);

    double ce = 0.0, sl = 0.0, npd = 0.0;
    const int lbl = labels[row];
    unsigned key = 0u;
    if (lbl > 0) {
        ce  = (double)(lse - rp[lbl]);
        npd = 1.0;
        const float4 pv = ((const float4*)pred)[row];
        const float4 gv = ((const float4*)gt)[row];
        float d;
        d = fabsf(pv.x - gv.x); sl += (d < 1.f) ? 0.5f * d * d : d - 0.5f;
        d = fabsf(pv.y - gv.y); sl += (d < 1.f) ? 0.5f * d * d : d - 0.5f;
        d = fabsf(pv.z - gv.z); sl += (d < 1.f) ? 0.5f * d * d : d - 0.5f;
        d = fabsf(pv.w - gv.w); sl += (d < 1.f) ? 0.5f * d * d : d - 0.5f;
    } else {
        key = __float_as_uint(lse - q[0].x) + 1u;   // bg>=0: order-preserving, >=1
    }
    keys[row] = key;

    #pragma unroll
    for (int o = 32; o; o >>= 1) {
        ce  += __shfl_xor(ce, o);
        sl  += __shfl_xor(sl, o);
        npd += __shfl_xor(npd, o);
    }
    const int wid = tid >> 6, lane = tid & 63;
    if (lane == 0) { s_red[wid][0] = ce; s_red[wid][1] = sl; s_red[wid][2] = npd; }
    __syncthreads();
    if (tid == 0) {
        double a = 0, b = 0, c = 0;
        for (int w = 0; w < 4; ++w) { a += s_red[w][0]; b += s_red[w][1]; c += s_red[w][2]; }
        partials[blockIdx.x * 3 + 0] = a;
        partials[blockIdx.x * 3 + 1] = b;
        partials[blockIdx.x * 3 + 2] = c;
    }
}

// One 1024-thread block per batch row. 9 keys/thread in registers. Exact
// K-th-largest via 256-way histogram-radix over [lo,hi] (<=5 passes, ~3
// barriers each) instead of ~28 barrier-serial binary-search iterations.
// Wave 0 also stripe-reduces partials. Ticket finalization unchanged.
__global__ __launch_bounds__(SEL_TPB) void mb_select(
    const unsigned* __restrict__ keys_g,
    const double* __restrict__ partials,
    double* __restrict__ acc,
    float* __restrict__ out)
{
    __shared__ unsigned whist[NWAVE][HPAD];     // 16448 B
    __shared__ unsigned tot[256];
    __shared__ unsigned s_np[16], s_mx[16], s_mn[16], s_cg[16];
    __shared__ double   s_sum[16];
    __shared__ double   s_pp[3];
    __shared__ unsigned s_K, s_lo, s_hi, s_bin, s_newA;

    const int b = blockIdx.x, tid = threadIdx.x;
    const int lane = tid & 63, wid = tid >> 6;

    // ---- (a) wave 0: stripe-reduce partials ----
    if (wid == 0) {
        double pce = 0, psl = 0, pnp = 0;
        const int j = b + (lane << 6);
        if (j < NBLK) {
            pce = partials[3 * j + 0];
            psl = partials[3 * j + 1];
            pnp = partials[3 * j + 2];
        }
        #pragma unroll
        for (int o = 32; o; o >>= 1) {
            pce += __shfl_xor(pce, o);
            psl += __shfl_xor(psl, o);
            pnp += __shfl_xor(pnp, o);
        }
        if (lane == 0) { s_pp[0] = pce; s_pp[1] = psl; s_pp[2] = pnp; }
    }

    // ---- (b) keys into registers (9/thread) ----
    unsigned k[SKPT];
    unsigned np = 0, mx = 0u, mn = 0xFFFFFFFFu;
    #pragma unroll
    for (int i = 0; i < SKPT; ++i) {
        unsigned key = 0u;
        if (i < 8 || tid < STAIL) {
            key = keys_g[b * NP + i * SEL_TPB + tid];
            np += (key == 0u) ? 1u : 0u;            // key==0 <=> positive
            if (key) { mx = max(mx, key); mn = min(mn, key); }
        }
        k[i] = key;                                  // invalid slots: 0 (inert)
    }

    #pragma unroll
    for (int o = 32; o; o >>= 1) {
        np += __shfl_xor(np, o);
        mx  = max(mx, __shfl_xor(mx, o));
        mn  = min(mn, __shfl_xor(mn, o));
    }
    if (lane == 0) { s_np[wid] = np; s_mx[wid] = mx; s_mn[wid] = mn; }
    __syncthreads();

    if (tid == 0) {
        unsigned npt = 0, MX = 0, MN = 0xFFFFFFFFu;
        for (int q = 0; q < 16; ++q) {
            npt += s_np[q];
            MX = max(MX, s_mx[q]); MN = min(MN, s_mn[q]);
        }
        atomicAdd(&acc[1], s_pp[0]);
        atomicAdd(&acc[2], s_pp[1]);
        atomicAdd(&acc[3], s_pp[2]);
        unsigned K = 3u * npt;
        const unsigned nneg = NP - npt;
        if (K > nneg) K = nneg;
        s_K = K; s_lo = MN; s_hi = MX;
    }
    __syncthreads();

    const unsigned K = s_K;
    if (K > 0) {
        // invariant: A = count(key > hi) < K <= A + count(key in [lo,hi])
        unsigned lo = s_lo, hi = s_hi, A = 0u;
        for (int pass = 0; pass < 5 && lo < hi; ++pass) {
            const unsigned span  = hi - lo;
            const unsigned width = span / 256u + 1u;   // 256 bins cover [lo,hi]

            for (int i = tid; i < NWAVE * HPAD; i += SEL_TPB)
                ((unsigned*)whist)[i] = 0u;
            __syncthreads();

            #pragma unroll
            for (int i = 0; i < SKPT; ++i) {
                const unsigned kk = k[i];
                if (kk >= lo && kk <= hi)
                    atomicAdd(&whist[wid][(kk - lo) / width], 1u);
            }
            __syncthreads();

            if (tid < 256) {
                unsigned t = 0;
                #pragma unroll
                for (int w = 0; w < NWAVE; ++w) t += whist[w][tid];
                tot[tid] = t;
            }
            __syncthreads();

            if (tid < 64) {
                const int l = tid;
                const unsigned c0 = tot[4 * l], c1 = tot[4 * l + 1];
                const unsigned c2 = tot[4 * l + 2], c3 = tot[4 * l + 3];
                const unsigned ls = c0 + c1 + c2 + c3;
                unsigned run = ls;                     // inclusive suffix over lanes
                #pragma unroll
                for (int off = 1; off < 64; off <<= 1) {
                    const unsigned o = __shfl_down(run, off);
                    if (l + off < 64) run += o;
                }
                unsigned above = A + (run - ls);       // count > top edge of lane's bins
                const unsigned cs[4] = {c3, c2, c1, c0};
                #pragma unroll
                for (int q = 0; q < 4; ++q) {
                    const unsigned c = cs[q];
                    if (above < K && above + c >= K) { // unique boundary bin
                        s_bin  = (unsigned)(4 * l + 3 - q);
                        s_newA = above;
                    }
                    above += c;
                }
            }
            __syncthreads();

            const unsigned j = s_bin;
            A = s_newA;
            const unsigned nlo = lo + j * width;
            unsigned nhi = nlo + width - 1u;
            if (nhi > hi) nhi = hi;
            lo = nlo; hi = nhi;
            __syncthreads();                           // s_bin/s_newA read by all
        }
        const unsigned V = lo;            // exact key of K-th largest (>=1)

        double ssum = 0.0; unsigned cgt = 0;
        #pragma unroll
        for (int i = 0; i < SKPT; ++i) {
            const unsigned kk = k[i];
            if (kk > V) { ssum += (double)__uint_as_float(kk - 1u); cgt++; }
        }
        #pragma unroll
        for (int o = 32; o; o >>= 1) { ssum += __shfl_xor(ssum, o); cgt += __shfl_xor(cgt, o); }
        if (lane == 0) { s_sum[wid] = ssum; s_cg[wid] = cgt; }
        __syncthreads();
        if (tid == 0) {
            double tot2 = 0.0; unsigned cg = 0;
            for (int q = 0; q < 16; ++q) { tot2 += s_sum[q]; cg += s_cg[q]; }
            tot2 += (double)(K - cg) * (double)__uint_as_float(V - 1u);  // ties at V
            atomicAdd(&acc[0], tot2);
        }
    }

    // ---- fused finalization: last block through the ticket writes out ----
    if (tid == 0) {
        __threadfence();
        const unsigned done = atomicAdd((unsigned*)(acc + 4), 1u);
        if (done == NB - 1) {
            __threadfence();
            const double topk = atomicAdd(&acc[0], 0.0);   // device-scope reads
            const double pce  = atomicAdd(&acc[1], 0.0);
            const double psl  = atomicAdd(&acc[2], 0.0);
            const double npd  = atomicAdd(&acc[3], 0.0);
            out[0] = (float)(psl / npd);            // smooth_l1 / num_pos
            out[1] = (float)((pce + topk) / npd);   // classification / num_pos
        }
    }
}

extern "C" void kernel_launch(void* const* d_in, const int* in_sizes, int n_in,
                              void* d_out, int out_size, void* d_ws, size_t ws_size,
                              hipStream_t stream)
{
    const float* conf   = (const float*)d_in[0];
    const float* pred   = (const float*)d_in[1];
    const int*   labels = (const int*)d_in[2];
    const float* gt     = (const float*)d_in[3];
    float* out = (float*)d_out;

    double*   acc      = (double*)d_ws;
    double*   partials = (double*)((char*)d_ws + PART_OFF);
    unsigned* keys     = (unsigned*)((char*)d_ws + KEY_OFF);

    mb_rows<<<NBLK, TPB, 0, stream>>>(conf, pred, gt, labels, keys, partials, acc);
    mb_select<<<NB, SEL_TPB, 0, stream>>>(keys, partials, acc, out);
}

// Round 19
// 48.849 us; speedup vs baseline: 2.7209x; 1.0156x over previous
//
#include <hip/hip_runtime.h>
#include <math.h>

#define NB 64
#define NP 8732
#define NC 81
#define NROWS (NB * NP)            // 558848 = 2183 * 256 exactly
#define TPB 256
#define NBLK (NROWS / TPB)         // 2183
#define SEL_TPB 512
#define SKPT 18                    // ceil(NP/512); i==17 valid only for tid<28
#define STAIL (NP - 17 * SEL_TPB)  // 28
#define NWAVE 8
#define HPAD 257                   // +1 pad per wave row

// ws layout:
//   acc      : double[8]        @ 0   [0]=topK_neg [1]=ce_pos [2]=sl1 [3]=num_pos [4]=ticket
//   partials : double[NBLK*3]   @ 64
//   keys     : uint[NROWS]      @ KEY_OFF   (0 = positive; else bits(bg)+1)
#define PART_OFF 64
#define PART_BYTES (((NBLK * 3 * 8 + 63) / 64) * 64)
#define KEY_OFF (PART_OFF + PART_BYTES)

__global__ __launch_bounds__(TPB) void mb_rows(
    const float* __restrict__ conf,
    const float* __restrict__ pred,
    const float* __restrict__ gt,
    const int*   __restrict__ labels,
    unsigned* __restrict__ keys,
    double* __restrict__ partials,
    double* __restrict__ acc)
{
    __shared__ double s_red[4][3];

    const int tid = threadIdx.x;
    const int row = blockIdx.x * TPB + tid;       // always < NROWS (exact grid)

    if (blockIdx.x == 0 && tid == 0) {
        acc[0] = 0.0; acc[1] = 0.0; acc[2] = 0.0; acc[3] = 0.0; acc[4] = 0.0;
    }

    const float* rp = conf + (size_t)row * NC;

    float4 q[20];
    #pragma unroll
    for (int i = 0; i < 20; ++i) __builtin_memcpy(&q[i], rp + 4 * i, 16);
    const float last = rp[80];

    float4 m4 = q[0];
    #pragma unroll
    for (int i = 1; i < 20; ++i) {
        m4.x = fmaxf(m4.x, q[i].x);
        m4.y = fmaxf(m4.y, q[i].y);
        m4.z = fmaxf(m4.z, q[i].z);
        m4.w = fmaxf(m4.w, q[i].w);
    }
    float M = fmaxf(fmaxf(m4.x, m4.y), fmaxf(m4.z, m4.w));
    M = fmaxf(M, last);

    float s = __expf(last - M);
    #pragma unroll
    for (int i = 0; i < 20; ++i)
        s += __expf(q[i].x - M) + __expf(q[i].y - M)
           + __expf(q[i].z - M) + __expf(q[i].w - M);

    const float lse = M + __logf(s);

    double ce = 0.0, sl = 0.0, npd = 0.0;
    const int lbl = labels[row];
    unsigned key = 0u;
    if (lbl > 0) {
        ce  = (double)(lse - rp[lbl]);
        npd = 1.0;
        const float4 pv = ((const float4*)pred)[row];
        const float4 gv = ((const float4*)gt)[row];
        float d;
        d = fabsf(pv.x - gv.x); sl += (d < 1.f) ? 0.5f * d * d : d - 0.5f;
        d = fabsf(pv.y - gv.y); sl += (d < 1.f) ? 0.5f * d * d : d - 0.5f;
        d = fabsf(pv.z - gv.z); sl += (d < 1.f) ? 0.5f * d * d : d - 0.5f;
        d = fabsf(pv.w - gv.w); sl += (d < 1.f) ? 0.5f * d * d : d - 0.5f;
    } else {
        key = __float_as_uint(lse - q[0].x) + 1u;   // bg>=0: order-preserving, >=1
    }
    keys[row] = key;

    #pragma unroll
    for (int o = 32; o; o >>= 1) {
        ce  += __shfl_xor(ce, o);
        sl  += __shfl_xor(sl, o);
        npd += __shfl_xor(npd, o);
    }
    const int wid = tid >> 6, lane = tid & 63;
    if (lane == 0) { s_red[wid][0] = ce; s_red[wid][1] = sl; s_red[wid][2] = npd; }
    __syncthreads();
    if (tid == 0) {
        double a = 0, b = 0, c = 0;
        for (int w = 0; w < 4; ++w) { a += s_red[w][0]; b += s_red[w][1]; c += s_red[w][2]; }
        partials[blockIdx.x * 3 + 0] = a;
        partials[blockIdx.x * 3 + 1] = b;
        partials[blockIdx.x * 3 + 2] = c;
    }
}

// One 512-thread block per batch row. 18 keys/thread in registers. Exact
// K-th-largest via 256-way histogram-radix, 2 barriers per pass: per-wave
// histograms make clear+accumulate wave-local; the cross-wave reduction is
// folded into the wave-0 boundary scan. Ticket finalization unchanged.
__global__ __launch_bounds__(SEL_TPB) void mb_select(
    const unsigned* __restrict__ keys_g,
    const double* __restrict__ partials,
    double* __restrict__ acc,
    float* __restrict__ out)
{
    __shared__ unsigned whist[NWAVE][HPAD];     // 8224 B
    __shared__ unsigned s_np[8], s_mx[8], s_mn[8], s_cg[8];
    __shared__ double   s_sum[8];
    __shared__ double   s_pp[3];
    __shared__ unsigned s_K, s_lo, s_hi, s_bin, s_newA;

    const int b = blockIdx.x, tid = threadIdx.x;
    const int lane = tid & 63, wid = tid >> 6;

    // ---- (a) wave 0: stripe-reduce partials (j = b + 64*lane covers NBLK) ----
    if (wid == 0) {
        double pce = 0, psl = 0, pnp = 0;
        const int j = b + (lane << 6);
        if (j < NBLK) {
            pce = partials[3 * j + 0];
            psl = partials[3 * j + 1];
            pnp = partials[3 * j + 2];
        }
        #pragma unroll
        for (int o = 32; o; o >>= 1) {
            pce += __shfl_xor(pce, o);
            psl += __shfl_xor(psl, o);
            pnp += __shfl_xor(pnp, o);
        }
        if (lane == 0) { s_pp[0] = pce; s_pp[1] = psl; s_pp[2] = pnp; }
    }

    // ---- (b) keys into registers (18/thread, no spill per R11) ----
    unsigned k[SKPT];
    unsigned np = 0, mx = 0u, mn = 0xFFFFFFFFu;
    #pragma unroll
    for (int i = 0; i < SKPT; ++i) {
        unsigned key = 0u;
        if (i < 17 || tid < STAIL) {
            key = keys_g[b * NP + i * SEL_TPB + tid];
            np += (key == 0u) ? 1u : 0u;            // key==0 <=> positive
            if (key) { mx = max(mx, key); mn = min(mn, key); }
        }
        k[i] = key;                                  // invalid slots: 0 (inert)
    }

    #pragma unroll
    for (int o = 32; o; o >>= 1) {
        np += __shfl_xor(np, o);
        mx  = max(mx, __shfl_xor(mx, o));
        mn  = min(mn, __shfl_xor(mn, o));
    }
    if (lane == 0) { s_np[wid] = np; s_mx[wid] = mx; s_mn[wid] = mn; }
    __syncthreads();

    if (tid == 0) {
        unsigned npt = 0, MX = 0, MN = 0xFFFFFFFFu;
        for (int q = 0; q < 8; ++q) {
            npt += s_np[q];
            MX = max(MX, s_mx[q]); MN = min(MN, s_mn[q]);
        }
        atomicAdd(&acc[1], s_pp[0]);
        atomicAdd(&acc[2], s_pp[1]);
        atomicAdd(&acc[3], s_pp[2]);
        unsigned K = 3u * npt;
        const unsigned nneg = NP - npt;
        if (K > nneg) K = nneg;
        s_K = K; s_lo = MN; s_hi = MX;
    }
    __syncthreads();

    const unsigned K = s_K;
    if (K > 0) {
        // invariant: A = count(key > hi) < K <= A + count(key in [lo,hi])
        unsigned lo = s_lo, hi = s_hi, A = 0u;
        for (int pass = 0; pass < 5 && lo < hi; ++pass) {
            const unsigned span  = hi - lo;
            const unsigned width = span / 256u + 1u;   // 256 bins cover [lo,hi]

            // wave-local clear of OUR histogram row (no barrier needed:
            // previous pass's scan finished before last barrier)
            #pragma unroll
            for (int i = 0; i < 4; ++i) {
                const int idx = lane + 64 * i;
                whist[wid][idx] = 0u;
            }
            if (lane == 0) whist[wid][256] = 0u;
            // wave-local accumulate (threads only touch whist[wid][*])
            #pragma unroll
            for (int i = 0; i < SKPT; ++i) {
                const unsigned kk = k[i];
                if (kk >= lo && kk <= hi)
                    atomicAdd(&whist[wid][(kk - lo) / width], 1u);
            }
            __syncthreads();                           // publish all wave rows

            if (tid < 64) {
                const int l = tid;
                unsigned c[4];
                #pragma unroll
                for (int q = 0; q < 4; ++q) {
                    unsigned t = 0;
                    #pragma unroll
                    for (int w = 0; w < NWAVE; ++w) t += whist[w][4 * l + q];
                    c[q] = t;
                }
                const unsigned ls = c[0] + c[1] + c[2] + c[3];
                unsigned run = ls;                     // inclusive suffix over lanes
                #pragma unroll
                for (int off = 1; off < 64; off <<= 1) {
                    const unsigned o = __shfl_down(run, off);
                    if (l + off < 64) run += o;
                }
                unsigned above = A + (run - ls);       // count > top edge of lane's bins
                #pragma unroll
                for (int q = 3; q >= 0; --q) {
                    const unsigned cc = c[q];
                    if (above < K && above + cc >= K) {  // unique boundary bin
                        s_bin  = (unsigned)(4 * l + q);
                        s_newA = above;
                    }
                    above += cc;
                }
            }
            __syncthreads();                           // publish s_bin/s_newA

            const unsigned j = s_bin;
            A = s_newA;
            const unsigned nlo = lo + j * width;
            unsigned nhi = nlo + width - 1u;
            if (nhi > hi) nhi = hi;
            lo = nlo; hi = nhi;
        }
        const unsigned V = lo;            // exact key of K-th largest (>=1)

        double ssum = 0.0; unsigned cgt = 0;
        #pragma unroll
        for (int i = 0; i < SKPT; ++i) {
            const unsigned kk = k[i];
            if (kk > V) { ssum += (double)__uint_as_float(kk - 1u); cgt++; }
        }
        #pragma unroll
        for (int o = 32; o; o >>= 1) { ssum += __shfl_xor(ssum, o); cgt += __shfl_xor(cgt, o); }
        if (lane == 0) { s_sum[wid] = ssum; s_cg[wid] = cgt; }
        __syncthreads();
        if (tid == 0) {
            double tot = 0.0; unsigned cg = 0;
            for (int q = 0; q < 8; ++q) { tot += s_sum[q]; cg += s_cg[q]; }
            tot += (double)(K - cg) * (double)__uint_as_float(V - 1u);  // ties at V
            atomicAdd(&acc[0], tot);
        }
    }

    // ---- fused finalization: last block through the ticket writes out ----
    if (tid == 0) {
        __threadfence();
        const unsigned done = atomicAdd((unsigned*)(acc + 4), 1u);
        if (done == NB - 1) {
            __threadfence();
            const double topk = atomicAdd(&acc[0], 0.0);   // device-scope reads
            const double pce  = atomicAdd(&acc[1], 0.0);
            const double psl  = atomicAdd(&acc[2], 0.0);
            const double npd  = atomicAdd(&acc[3], 0.0);
            out[0] = (float)(psl / npd);            // smooth_l1 / num_pos
            out[1] = (float)((pce + topk) / npd);   // classification / num_pos
        }
    }
}

extern "C" void kernel_launch(void* const* d_in, const int* in_sizes, int n_in,
                              void* d_out, int out_size, void* d_ws, size_t ws_size,
                              hipStream_t stream)
{
    const float* conf   = (const float*)d_in[0];
    const float* pred   = (const float*)d_in[1];
    const int*   labels = (const int*)d_in[2];
    const float* gt     = (const float*)d_in[3];
    float* out = (float*)d_out;

    double*   acc      = (double*)d_ws;
    double*   partials = (double*)((char*)d_ws + PART_OFF);
    unsigned* keys     = (unsigned*)((char*)d_ws + KEY_OFF);

    mb_rows<<<NBLK, TPB, 0, stream>>>(conf, pred, gt, labels, keys, partials, acc);
    mb_select<<<NB, SEL_TPB, 0, stream>>>(keys, partials, acc, out);
}